// Round 1
// baseline (1341.528 us; speedup 1.0000x reference)
//
#include <hip/hip_runtime.h>
#include <math.h>

#define SD 7
#define HID 64
#define NITER 10

// tanh-approx GELU, matching jax.nn.gelu(approximate=True):
// 0.5*x*(1+tanh(sqrt(2/pi)*(x+0.044715*x^3)))
__device__ __forceinline__ float gelu_tanh(float x) {
    const float kA = 0.7978845608028654f;  // sqrt(2/pi)
    const float kB = 0.044715f;
    float x3 = x * x * x;
    float y  = kA * fmaf(kB, x3, x);
    float ay = fabsf(y);
    float e  = __expf(-2.0f * ay);                 // exp(-2|y|)
    float t  = __fdividef(1.0f - e, 1.0f + e);     // tanh(|y|)
    t = copysignf(t, y);
    return 0.5f * x * (1.0f + t);
}

__global__ __launch_bounds__(256)
void strange_loop_kernel(const float* __restrict__ s7,
                         const float* __restrict__ w0,
                         const float* __restrict__ b0,
                         const float* __restrict__ lns,
                         const float* __restrict__ lnb,
                         const float* __restrict__ ow,
                         const float* __restrict__ ob,
                         float* __restrict__ out_mu,
                         float* __restrict__ out_cv,
                         int Bn)
{
    int row = blockIdx.x * blockDim.x + threadIdx.x;
    if (row >= Bn) row = Bn - 1;   // clamp (no divergent CF; dup write benign)

    // ---- load context (28 B/row) ----
    float s[SD];
    #pragma unroll
    for (int k = 0; k < SD; ++k) s[k] = s7[(size_t)row * SD + k];

    // ---- iteration-invariant half of fc0: ctx[j] = sum_k s[k]*W0[7+k][j] ----
    float ctx[HID];
    #pragma unroll
    for (int j = 0; j < HID; ++j) ctx[j] = s[0] * w0[SD * HID + j];
    #pragma unroll
    for (int k = 1; k < SD; ++k) {
        const float sk = s[k];
        #pragma unroll
        for (int j = 0; j < HID; ++j)
            ctx[j] = fmaf(sk, w0[(SD + k) * HID + j], ctx[j]);
    }

    const float mu0 = 0.37796447300922720f;  // 1/sqrt(7) in f32
    float mu[SD];
    #pragma unroll
    for (int i = 0; i < SD; ++i) mu[i] = mu0;

    float conv = 0.0f;

    #pragma unroll 1
    for (int it = 0; it < NITER; ++it) {
        // ---- fc0 mu-part + ctx + bias ----
        float x[HID];
        #pragma unroll
        for (int j = 0; j < HID; ++j) x[j] = mu[0] * w0[j];
        #pragma unroll
        for (int k = 1; k < SD; ++k) {
            const float mk = mu[k];
            #pragma unroll
            for (int j = 0; j < HID; ++j)
                x[j] = fmaf(mk, w0[k * HID + j], x[j]);
        }
        #pragma unroll
        for (int j = 0; j < HID; ++j) x[j] = (x[j] + ctx[j]) + b0[j];

        // ---- LayerNorm over 64 ----
        float s0 = 0.f, s1 = 0.f, s2 = 0.f, s3 = 0.f;
        #pragma unroll
        for (int j = 0; j < HID; j += 4) {
            s0 += x[j]; s1 += x[j + 1]; s2 += x[j + 2]; s3 += x[j + 3];
        }
        float mean = ((s0 + s1) + (s2 + s3)) * (1.0f / HID);
        float v0 = 0.f, v1 = 0.f, v2 = 0.f, v3 = 0.f;
        #pragma unroll
        for (int j = 0; j < HID; j += 4) {
            float a0 = x[j] - mean, a1 = x[j + 1] - mean;
            float a2 = x[j + 2] - mean, a3 = x[j + 3] - mean;
            v0 = fmaf(a0, a0, v0); v1 = fmaf(a1, a1, v1);
            v2 = fmaf(a2, a2, v2); v3 = fmaf(a3, a3, v3);
            x[j] = a0; x[j + 1] = a1; x[j + 2] = a2; x[j + 3] = a3;
        }
        float var  = ((v0 + v1) + (v2 + v3)) * (1.0f / HID);
        float rstd = 1.0f / sqrtf(var + 1e-6f);

        // ---- scale/shift + GELU ----
        #pragma unroll
        for (int j = 0; j < HID; ++j)
            x[j] = gelu_tanh(fmaf(x[j] * rstd, lns[j], lnb[j]));

        // ---- out matmul [1x64]x[64x7] + bias ----
        float u[SD];
        #pragma unroll
        for (int i = 0; i < SD; ++i) u[i] = x[0] * ow[i];
        #pragma unroll
        for (int j = 1; j < HID; ++j) {
            const float xj = x[j];
            #pragma unroll
            for (int i = 0; i < SD; ++i)
                u[i] = fmaf(xj, ow[j * SD + i], u[i]);
        }
        #pragma unroll
        for (int i = 0; i < SD; ++i) u[i] += ob[i];

        // ---- L2 normalize ----
        float ss = 0.f;
        #pragma unroll
        for (int i = 0; i < SD; ++i) ss = fmaf(u[i], u[i], ss);
        float nrm = sqrtf(ss);
        float inv = 1.0f / (nrm + 1e-8f);

        // ---- damped update + convergence ----
        float dd = 0.f;
        #pragma unroll
        for (int i = 0; i < SD; ++i) {
            float un = u[i] * inv;
            float mn = 0.5f * mu[i] + 0.5f * un;
            float d  = mn - mu[i];
            dd = fmaf(d, d, dd);
            mu[i] = mn;
        }
        if (sqrtf(dd) < 1e-4f) conv = 1.0f;
    }

    #pragma unroll
    for (int i = 0; i < SD; ++i) out_mu[(size_t)row * SD + i] = mu[i];
    out_cv[row] = conv;
}

extern "C" void kernel_launch(void* const* d_in, const int* in_sizes, int n_in,
                              void* d_out, int out_size, void* d_ws, size_t ws_size,
                              hipStream_t stream) {
    const float* s7  = (const float*)d_in[0];
    const float* w0  = (const float*)d_in[1];
    const float* b0  = (const float*)d_in[2];
    const float* lns = (const float*)d_in[3];
    const float* lnb = (const float*)d_in[4];
    const float* ow  = (const float*)d_in[5];
    const float* ob  = (const float*)d_in[6];
    const int Bn = in_sizes[0] / SD;

    float* out_mu = (float*)d_out;
    float* out_cv = out_mu + (size_t)Bn * SD;

    const int block = 256;
    const int grid  = (Bn + block - 1) / block;
    hipLaunchKernelGGL(strange_loop_kernel, dim3(grid), dim3(block), 0, stream,
                       s7, w0, b0, lns, lnb, ow, ob, out_mu, out_cv, Bn);
}

// Round 2
// 1220.651 us; speedup vs baseline: 1.0990x; 1.0990x over previous
//
#include <hip/hip_runtime.h>
#include <math.h>

#define SD 7
#define HID 64
#define NITER 10

// gelu(x) (tanh approx) == x * sigmoid(2*y), y = sqrt(2/pi)*(x + 0.044715 x^3)
// => g = x / (1 + exp(-1.5957691216*(x + 0.044715 x^3)))
__device__ __forceinline__ float gelu_tanh(float x) {
    const float kC = -1.5957691216057308f;   // -2*sqrt(2/pi)
    const float kB = 0.044715f;
    float x2 = x * x;
    float x3 = x2 * x;
    float z  = kC * fmaf(kB, x3, x);
    float e  = __expf(z);                    // v_mul + v_exp
    return __fdividef(x, 1.0f + e);          // v_add + v_rcp + v_mul
}

__global__ __launch_bounds__(256, 2)
void strange_loop_kernel(const float* __restrict__ s7,
                         const float* __restrict__ w0,
                         const float* __restrict__ b0,
                         const float* __restrict__ lns,
                         const float* __restrict__ lnb,
                         const float* __restrict__ ow,
                         const float* __restrict__ ob,
                         float* __restrict__ out_mu,
                         float* __restrict__ out_cv,
                         int Bn)
{
    int row = blockIdx.x * blockDim.x + threadIdx.x;
    if (row >= Bn) row = Bn - 1;   // clamp: keeps control flow uniform

    // ---- load context (28 B/row) ----
    float s[SD];
    #pragma unroll
    for (int k = 0; k < SD; ++k) s[k] = s7[(size_t)row * SD + k];

    // ---- iteration-invariant: base[j] = b0[j] + sum_k s[k]*W0[7+k][j] ----
    float base[HID];
    #pragma unroll
    for (int j = 0; j < HID; ++j) base[j] = fmaf(s[0], w0[SD * HID + j], b0[j]);
    #pragma unroll
    for (int k = 1; k < SD; ++k) {
        const float sk = s[k];
        #pragma unroll
        for (int j = 0; j < HID; ++j)
            base[j] = fmaf(sk, w0[(SD + k) * HID + j], base[j]);
    }

    const float mu0 = 0.37796447300922720f;  // 1/sqrt(7)
    float mu[SD];
    #pragma unroll
    for (int i = 0; i < SD; ++i) mu[i] = mu0;

    float conv = 0.0f;

    #pragma unroll 1
    for (int it = 0; it < NITER; ++it) {
        // ---- fc0: x[j] = base[j] + sum_k mu[k]*W0[k][j] ----
        float x[HID];
        #pragma unroll
        for (int j = 0; j < HID; ++j) x[j] = fmaf(mu[0], w0[j], base[j]);
        #pragma unroll
        for (int k = 1; k < SD; ++k) {
            const float mk = mu[k];
            #pragma unroll
            for (int j = 0; j < HID; ++j)
                x[j] = fmaf(mk, w0[k * HID + j], x[j]);
        }

        // ---- LayerNorm over 64 (two-pass, matches jnp.var) ----
        float s0 = 0.f, s1 = 0.f, s2 = 0.f, s3 = 0.f;
        #pragma unroll
        for (int j = 0; j < HID; j += 4) {
            s0 += x[j]; s1 += x[j + 1]; s2 += x[j + 2]; s3 += x[j + 3];
        }
        float mean = ((s0 + s1) + (s2 + s3)) * (1.0f / HID);
        float v0 = 0.f, v1 = 0.f, v2 = 0.f, v3 = 0.f;
        #pragma unroll
        for (int j = 0; j < HID; j += 4) {
            float a0 = x[j] - mean, a1 = x[j + 1] - mean;
            float a2 = x[j + 2] - mean, a3 = x[j + 3] - mean;
            v0 = fmaf(a0, a0, v0); v1 = fmaf(a1, a1, v1);
            v2 = fmaf(a2, a2, v2); v3 = fmaf(a3, a3, v3);
            x[j] = a0; x[j + 1] = a1; x[j + 2] = a2; x[j + 3] = a3;
        }
        float var  = ((v0 + v1) + (v2 + v3)) * (1.0f / HID);
        float rstd = 1.0f / sqrtf(var + 1e-6f);

        // ---- scale/shift + GELU ----
        #pragma unroll
        for (int j = 0; j < HID; ++j)
            x[j] = gelu_tanh(fmaf(x[j] * rstd, lns[j], lnb[j]));

        // ---- out matmul [1x64]x[64x7], bias folded into init ----
        float u[SD];
        #pragma unroll
        for (int i = 0; i < SD; ++i) u[i] = fmaf(x[0], ow[i], ob[i]);
        #pragma unroll
        for (int j = 1; j < HID; ++j) {
            const float xj = x[j];
            #pragma unroll
            for (int i = 0; i < SD; ++i)
                u[i] = fmaf(xj, ow[j * SD + i], u[i]);
        }

        // ---- L2 normalize ----
        float ss = 0.f;
        #pragma unroll
        for (int i = 0; i < SD; ++i) ss = fmaf(u[i], u[i], ss);
        float inv = __fdividef(1.0f, sqrtf(ss) + 1e-8f);

        // ---- damped update + convergence ----
        float dd = 0.f;
        #pragma unroll
        for (int i = 0; i < SD; ++i) {
            float un = u[i] * inv;
            float mn = 0.5f * mu[i] + 0.5f * un;
            float d  = mn - mu[i];
            dd = fmaf(d, d, dd);
            mu[i] = mn;
        }
        if (sqrtf(dd) < 1e-4f) conv = 1.0f;
    }

    #pragma unroll
    for (int i = 0; i < SD; ++i) out_mu[(size_t)row * SD + i] = mu[i];
    out_cv[row] = conv;
}

extern "C" void kernel_launch(void* const* d_in, const int* in_sizes, int n_in,
                              void* d_out, int out_size, void* d_ws, size_t ws_size,
                              hipStream_t stream) {
    const float* s7  = (const float*)d_in[0];
    const float* w0  = (const float*)d_in[1];
    const float* b0  = (const float*)d_in[2];
    const float* lns = (const float*)d_in[3];
    const float* lnb = (const float*)d_in[4];
    const float* ow  = (const float*)d_in[5];
    const float* ob  = (const float*)d_in[6];
    const int Bn = in_sizes[0] / SD;

    float* out_mu = (float*)d_out;
    float* out_cv = out_mu + (size_t)Bn * SD;

    const int block = 256;
    const int grid  = (Bn + block - 1) / block;
    hipLaunchKernelGGL(strange_loop_kernel, dim3(grid), dim3(block), 0, stream,
                       s7, w0, b0, lns, lnb, ow, ob, out_mu, out_cv, Bn);
}

// Round 3
// 1067.689 us; speedup vs baseline: 1.2565x; 1.1433x over previous
//
#include <hip/hip_runtime.h>
#include <math.h>

#define SD 7
#define HID 64
#define NQ 16      // HID/4
#define NITER 10

typedef float f4 __attribute__((ext_vector_type(4)));

#define REP16(M) M(0) M(1) M(2) M(3) M(4) M(5) M(6) M(7) M(8) M(9) M(10) M(11) M(12) M(13) M(14) M(15)
#define REP15(M) M(1) M(2) M(3) M(4) M(5) M(6) M(7) M(8) M(9) M(10) M(11) M(12) M(13) M(14) M(15)
#define REP7(M)  M(0) M(1) M(2) M(3) M(4) M(5) M(6)

// r = fma(scalar, w, a) per component
__device__ __forceinline__ f4 vfma_s(float s, f4 w, f4 a) {
    f4 r;
    r.x = fmaf(s, w.x, a.x);
    r.y = fmaf(s, w.y, a.y);
    r.z = fmaf(s, w.z, a.z);
    r.w = fmaf(s, w.w, a.w);
    return r;
}
// r = fma(a, b, c) per component
__device__ __forceinline__ f4 vfma_v(f4 a, f4 b, f4 c) {
    f4 r;
    r.x = fmaf(a.x, b.x, c.x);
    r.y = fmaf(a.y, b.y, c.y);
    r.z = fmaf(a.z, b.z, c.z);
    r.w = fmaf(a.w, b.w, c.w);
    return r;
}

// gelu(x) (tanh approx) == x / (1 + exp(-2*sqrt(2/pi)*(x + 0.044715 x^3)))
// identical arithmetic to the passing round-1 kernel
__device__ __forceinline__ float gelu_t(float x) {
    const float kC = -1.5957691216057308f;   // -2*sqrt(2/pi)
    const float kB = 0.044715f;
    float x2 = x * x;
    float x3 = x2 * x;
    float z  = kC * fmaf(kB, x3, x);
    float e  = __expf(z);
    return __fdividef(x, 1.0f + e);
}

__global__ __launch_bounds__(256, 2)
void strange_loop_kernel(const float* __restrict__ s7,
                         const float* __restrict__ w0,
                         const float* __restrict__ b0,
                         const float* __restrict__ lns,
                         const float* __restrict__ lnb,
                         const float* __restrict__ ow,
                         const float* __restrict__ ob,
                         float* __restrict__ out_mu,
                         float* __restrict__ out_cv,
                         int Bn)
{
    int row = blockIdx.x * blockDim.x + threadIdx.x;
    if (row >= Bn) row = Bn - 1;   // clamp: uniform control flow, dup write benign

    const f4* __restrict__ w0v  = (const f4*)w0;    // [14][NQ]
    const f4* __restrict__ b0v  = (const f4*)b0;    // [NQ]
    const f4* __restrict__ lnsv = (const f4*)lns;
    const f4* __restrict__ lnbv = (const f4*)lnb;

    float s[SD];
#define LD_S(k) s[k] = s7[(size_t)row * SD + (k)];
    REP7(LD_S)

    // iteration-invariant: B[q] = b0 + sum_k s[k] * W0[7+k][.]
    f4 B[NQ];
#define INITB(q) { f4 a = b0v[q]; \
    a = vfma_s(s[0], w0v[(SD + 0) * NQ + (q)], a); \
    a = vfma_s(s[1], w0v[(SD + 1) * NQ + (q)], a); \
    a = vfma_s(s[2], w0v[(SD + 2) * NQ + (q)], a); \
    a = vfma_s(s[3], w0v[(SD + 3) * NQ + (q)], a); \
    a = vfma_s(s[4], w0v[(SD + 4) * NQ + (q)], a); \
    a = vfma_s(s[5], w0v[(SD + 5) * NQ + (q)], a); \
    a = vfma_s(s[6], w0v[(SD + 6) * NQ + (q)], a); \
    B[q] = a; }
    REP16(INITB)

    float mu[SD];
#define INITMU(i) mu[i] = 0.37796447300922720f;   // 1/sqrt(7)
    REP7(INITMU)
    float conv = 0.0f;

#pragma unroll 1
    for (int it = 0; it < NITER; ++it) {
        // ---- fc0: x = B + sum_k mu[k]*W0[k][.] ----
        f4 x[NQ];
#define FC0(q) { f4 a = vfma_s(mu[0], w0v[0 * NQ + (q)], B[q]); \
        a = vfma_s(mu[1], w0v[1 * NQ + (q)], a); \
        a = vfma_s(mu[2], w0v[2 * NQ + (q)], a); \
        a = vfma_s(mu[3], w0v[3 * NQ + (q)], a); \
        a = vfma_s(mu[4], w0v[4 * NQ + (q)], a); \
        a = vfma_s(mu[5], w0v[5 * NQ + (q)], a); \
        a = vfma_s(mu[6], w0v[6 * NQ + (q)], a); \
        x[q] = a; }
        REP16(FC0)

        // ---- LayerNorm (two-pass, striped partials == round-1 order) ----
        f4 sacc = x[0];
#define SAC(q) sacc += x[q];
        REP15(SAC)
        float mean = ((sacc.x + sacc.y) + (sacc.z + sacc.w)) * (1.0f / HID);

        f4 vacc = {0.f, 0.f, 0.f, 0.f};
#define VAC(q) { f4 a = x[q] - mean; vacc = vfma_v(a, a, vacc); x[q] = a; }
        REP16(VAC)
        float var  = ((vacc.x + vacc.y) + (vacc.z + vacc.w)) * (1.0f / HID);
        float rstd = 1.0f / sqrtf(var + 1e-6f);

        // ---- scale/shift + GELU ----
#define GEL(q) { f4 a = x[q]; f4 sc = lnsv[q]; f4 sh = lnbv[q]; \
        a.x = gelu_t(fmaf(a.x * rstd, sc.x, sh.x)); \
        a.y = gelu_t(fmaf(a.y * rstd, sc.y, sh.y)); \
        a.z = gelu_t(fmaf(a.z * rstd, sc.z, sh.z)); \
        a.w = gelu_t(fmaf(a.w * rstd, sc.w, sh.w)); \
        x[q] = a; }
        REP16(GEL)

        // ---- out matmul [1x64]x[64x7], bias in init; j ascending ----
        float u[SD];
#define IU(i) u[i] = fmaf(x[0].x, ow[i], ob[i]);
        REP7(IU)
#define OUT1(j, xj) { const float xx = (xj); \
        u[0] = fmaf(xx, ow[(j) * SD + 0], u[0]); \
        u[1] = fmaf(xx, ow[(j) * SD + 1], u[1]); \
        u[2] = fmaf(xx, ow[(j) * SD + 2], u[2]); \
        u[3] = fmaf(xx, ow[(j) * SD + 3], u[3]); \
        u[4] = fmaf(xx, ow[(j) * SD + 4], u[4]); \
        u[5] = fmaf(xx, ow[(j) * SD + 5], u[5]); \
        u[6] = fmaf(xx, ow[(j) * SD + 6], u[6]); }
#define OUTQ(q) { if ((q) != 0) OUT1(4*(q)+0, x[q].x) \
        OUT1(4*(q)+1, x[q].y) \
        OUT1(4*(q)+2, x[q].z) \
        OUT1(4*(q)+3, x[q].w) }
        REP16(OUTQ)

        // ---- L2 normalize ----
        float ss = 0.f;
#define SSQ(i) ss = fmaf(u[i], u[i], ss);
        REP7(SSQ)
        float inv = __fdividef(1.0f, sqrtf(ss) + 1e-8f);

        // ---- damped update + convergence ----
        float dd = 0.f;
#define UPD(i) { float un = u[i] * inv; float mn = 0.5f * mu[i] + 0.5f * un; \
        float d = mn - mu[i]; dd = fmaf(d, d, dd); mu[i] = mn; }
        REP7(UPD)
        if (sqrtf(dd) < 1e-4f) conv = 1.0f;
    }

#define ST(i) out_mu[(size_t)row * SD + (i)] = mu[i];
    REP7(ST)
    out_cv[row] = conv;
}

extern "C" void kernel_launch(void* const* d_in, const int* in_sizes, int n_in,
                              void* d_out, int out_size, void* d_ws, size_t ws_size,
                              hipStream_t stream) {
    const float* s7  = (const float*)d_in[0];
    const float* w0  = (const float*)d_in[1];
    const float* b0  = (const float*)d_in[2];
    const float* lns = (const float*)d_in[3];
    const float* lnb = (const float*)d_in[4];
    const float* ow  = (const float*)d_in[5];
    const float* ob  = (const float*)d_in[6];
    const int Bn = in_sizes[0] / SD;

    float* out_mu = (float*)d_out;
    float* out_cv = out_mu + (size_t)Bn * SD;

    const int block = 256;
    const int grid  = (Bn + block - 1) / block;
    hipLaunchKernelGGL(strange_loop_kernel, dim3(grid), dim3(block), 0, stream,
                       s7, w0, b0, lns, lnb, ow, ob, out_mu, out_cv, Bn);
}